// Round 11
// baseline (100.330 us; speedup 1.0000x reference)
//
#include <hip/hip_runtime.h>
#include <hip/hip_bf16.h>

typedef __bf16 bf16x8 __attribute__((ext_vector_type(8)));
typedef float  f32x4  __attribute__((ext_vector_type(4)));

// freqs[i] = 10000^(-i/16) = 10^(-i/4), i=0..7 (odd k-chunks scale by 1e-2)
__constant__ __device__ const float FREQ8[8] = {
    1.0f, 0.5623413251903491f, 0.31622776601683794f, 0.17782794100389228f,
    0.1f, 0.05623413251903491f, 0.031622776601683794f, 0.017782794100389228f };

// R11: TWO-DISPATCH serialization (final structural probe).
// Ladder: dual-stream interleaved 108 -> per-wave split (R9) 98.2 ->
// temporal phase split, one kernel (R10) 95.2. Residual theory: the
// phase-transition window still mixes both write streams. Fix: two
// back-to-back dispatches in the graph — kernel 1 writes ALL attn,
// kernel 2 writes ALL emb. Zero stream mixing at any instant.
// MFMA mapping (R3/R5): A-frag=W (row=lane&15->e), B-frag=emb
// (col=lane&15->point), D: col->point, 4 consecutive e per lane -> dwordx4.
// Plain stores (nontemporal = 2x slower, R4). No LDS.

template<bool POW2>
__global__ __launch_bounds__(256, 5) void relds_attn(
    const float* __restrict__ pos,   // [B,N,3]
    const float* __restrict__ tim,   // [B,N]
    const float* __restrict__ W,     // [32,32] row-major W[e][d]
    const float* __restrict__ bias,  // [32]
    float* __restrict__ out_attn,    // f32 [P,32]
    int N, int NN, int P, int logN)
{
    const int tid  = threadIdx.x;
    const int lane = tid & 63;
    const int wave = tid >> 6;
    const int row  = lane & 15;
    const int kb   = lane >> 4;

    const int wbase = blockIdx.x * 256 + wave * 64;
    if (wbase >= P) return;

    // ---- A fragments (W) + bias quads; L1/L2-resident ----
    bf16x8 Wf[2];
    f32x4  bq[2];
    #pragma unroll
    for (int n = 0; n < 2; ++n) {
        const int e = n * 16 + row;
        const float4 wA = *reinterpret_cast<const float4*>(W + e * 32 + kb * 8);
        const float4 wB = *reinterpret_cast<const float4*>(W + e * 32 + kb * 8 + 4);
        Wf[n][0] = (__bf16)wA.x; Wf[n][1] = (__bf16)wA.y;
        Wf[n][2] = (__bf16)wA.z; Wf[n][3] = (__bf16)wA.w;
        Wf[n][4] = (__bf16)wB.x; Wf[n][5] = (__bf16)wB.y;
        Wf[n][6] = (__bf16)wB.z; Wf[n][7] = (__bf16)wB.w;
        const float4 bb = *reinterpret_cast<const float4*>(bias + n * 16 + kb * 4);
        bq[n][0] = bb.x; bq[n][1] = bb.y; bq[n][2] = bb.z; bq[n][3] = bb.w;
    }

    constexpr float INV2PI = 0.15915494309189535f;
    const float premul = INV2PI * ((kb & 1) ? 0.01f : 1.0f);
    const float qoff   = (kb >= 2) ? 0.25f : 0.0f;   // cos(z) = sin(z + 1/4 rev)

    #pragma unroll
    for (int t = 0; t < 4; ++t) {
        const int q  = wbase + t * 16 + row;
        const int qc = (q < P) ? q : (P - 1);
        int in_n, in_m;
        if (POW2) {
            in_n = qc >> logN;
            in_m = ((qc >> (2 * logN)) << logN) | (qc & (N - 1));
        } else {
            const int b_ = qc / NN; const int r_ = qc - b_ * NN;
            const int n_ = r_ / N;  const int m_ = r_ - n_ * N;
            in_n = b_ * N + n_;     in_m = b_ * N + m_;
        }
        const float dx = pos[in_n * 3 + 0] - pos[in_m * 3 + 0];
        const float dy = pos[in_n * 3 + 1] - pos[in_m * 3 + 1];
        const float dz = pos[in_n * 3 + 2] - pos[in_m * 3 + 2];
        const float dt = (tim[in_n] - tim[in_m]) * 18.0f;  // TIME_SCALE
        const float ds2 = dx * dx + dy * dy + dz * dz - dt * dt;
        const float d   = copysignf(sqrtf(fabsf(ds2)), ds2);
        const float x   = 1024.0f * fminf(4.0f, fmaxf(-4.0f, d));
        const float xr  = x * premul;

        bf16x8 Af;
        #pragma unroll
        for (int j = 0; j < 8; ++j) {
            float rr = fmaf(xr, FREQ8[j], qoff);
            rr -= floorf(rr);
            Af[j] = (__bf16)__builtin_amdgcn_sinf(rr);
        }
        f32x4 acc0 = __builtin_amdgcn_mfma_f32_16x16x32_bf16(Wf[0], Af, bq[0], 0, 0, 0);
        f32x4 acc1 = __builtin_amdgcn_mfma_f32_16x16x32_bf16(Wf[1], Af, bq[1], 0, 0, 0);

        if (q < P) {
            float* ap = out_attn + (size_t)q * 32 + kb * 4;
            *reinterpret_cast<f32x4*>(ap)      = acc0;  // e = kb*4 .. +3
            *reinterpret_cast<f32x4*>(ap + 16) = acc1;  // e = 16 + kb*4 .. +3
        }
    }
}

template<bool POW2>
__global__ __launch_bounds__(256, 5) void relds_emb(
    const float* __restrict__ pos,   // [B,N,3]
    const float* __restrict__ tim,   // [B,N]
    float* __restrict__ out_emb,     // f32 [P,32]
    int N, int NN, int P, int logN)
{
    const int tid  = threadIdx.x;
    const int lane = tid & 63;
    const int wave = tid >> 6;
    const int row  = lane & 15;
    const int kb   = lane >> 4;

    const int wbase = blockIdx.x * 256 + wave * 64;
    if (wbase >= P) return;

    constexpr float INV2PI = 0.15915494309189535f;
    const float premul = INV2PI * ((kb & 1) ? 0.01f : 1.0f);
    const float qoff   = (kb >= 2) ? 0.25f : 0.0f;

    #pragma unroll
    for (int t = 0; t < 4; ++t) {
        const int q  = wbase + t * 16 + row;
        const int qc = (q < P) ? q : (P - 1);
        int in_n, in_m;
        if (POW2) {
            in_n = qc >> logN;
            in_m = ((qc >> (2 * logN)) << logN) | (qc & (N - 1));
        } else {
            const int b_ = qc / NN; const int r_ = qc - b_ * NN;
            const int n_ = r_ / N;  const int m_ = r_ - n_ * N;
            in_n = b_ * N + n_;     in_m = b_ * N + m_;
        }
        const float dx = pos[in_n * 3 + 0] - pos[in_m * 3 + 0];
        const float dy = pos[in_n * 3 + 1] - pos[in_m * 3 + 1];
        const float dz = pos[in_n * 3 + 2] - pos[in_m * 3 + 2];
        const float dt = (tim[in_n] - tim[in_m]) * 18.0f;
        const float ds2 = dx * dx + dy * dy + dz * dz - dt * dt;
        const float d   = copysignf(sqrtf(fabsf(ds2)), ds2);
        const float x   = 1024.0f * fminf(4.0f, fmaxf(-4.0f, d));
        const float xr  = x * premul;

        float v[8];
        #pragma unroll
        for (int j = 0; j < 8; ++j) {
            float rr = fmaf(xr, FREQ8[j], qoff);
            rr -= floorf(rr);
            v[j] = __builtin_amdgcn_sinf(rr);
        }

        if (q < P) {  // lane owns dims kb*8..kb*8+7 of point q
            float* ep = out_emb + (size_t)q * 32 + kb * 8;
            f32x4 e0 = { v[0], v[1], v[2], v[3] };
            f32x4 e1 = { v[4], v[5], v[6], v[7] };
            reinterpret_cast<f32x4*>(ep)[0] = e0;
            reinterpret_cast<f32x4*>(ep)[1] = e1;
        }
    }
}

extern "C" void kernel_launch(void* const* d_in, const int* in_sizes, int n_in,
                              void* d_out, int out_size, void* d_ws, size_t ws_size,
                              hipStream_t stream) {
    const float* pos  = (const float*)d_in[0];
    const float* tim  = (const float*)d_in[1];
    const float* W    = (const float*)d_in[2];
    const float* bias = (const float*)d_in[3];

    const int BN = in_sizes[1];          // B*N
    const int P  = out_size / 64;        // B*N*N
    const int N  = P / BN;
    const int NN = N * N;

    int logN = 0;
    while ((1 << logN) < N) ++logN;
    const bool pow2 = ((1 << logN) == N);

    float* out_attn = (float*)d_out;
    float* out_emb  = out_attn + (size_t)out_size / 2;

    const int nblk = (P + 255) / 256;
    if (pow2) {
        relds_attn<true><<<nblk, 256, 0, stream>>>(pos, tim, W, bias, out_attn, N, NN, P, logN);
        relds_emb<true><<<nblk, 256, 0, stream>>>(pos, tim, out_emb, N, NN, P, logN);
    } else {
        relds_attn<false><<<nblk, 256, 0, stream>>>(pos, tim, W, bias, out_attn, N, NN, P, logN);
        relds_emb<false><<<nblk, 256, 0, stream>>>(pos, tim, out_emb, N, NN, P, logN);
    }
}

// Round 12
// 94.693 us; speedup vs baseline: 1.0595x; 1.0595x over previous
//
#include <hip/hip_runtime.h>
#include <hip/hip_bf16.h>

typedef __bf16 bf16x8 __attribute__((ext_vector_type(8)));
typedef float  f32x4  __attribute__((ext_vector_type(4)));

// freqs[i] = 10000^(-i/16) = 10^(-i/4), i=0..7 (odd k-chunks scale by 1e-2)
__constant__ __device__ const float FREQ8[8] = {
    1.0f, 0.5623413251903491f, 0.31622776601683794f, 0.17782794100389228f,
    0.1f, 0.05623413251903491f, 0.031622776601683794f, 0.017782794100389228f };

// FINAL (revert to R10, best @95.2us): phase-separated output specialization,
// single dispatch. Blocks [0,nblk) write attn only; [nblk,2nblk) write emb
// only. One write stream per wave (R9: +10us) and mostly-serial phases
// (R10: +3us); full two-dispatch serialization REGRESSED (R11: 100.3 — the
// extra dispatch tail costs more than the transition window, which actually
// overlaps phase-2 compute under phase-1 write drain).
// Falsified along the way: occupancy (R6), store-burst spread (R6), vmcnt
// load/store entanglement (R7), half-masked 64B segments (R8), nt-stores
// (R4: 2x slower — bypassing L2 write-combining). 536.9MB @ 6.7TB/s = 80us
// + launch/ramp ~5-8us + residual mixing => ~88-93us floor; 95.2 is 2-8% off.
// MFMA mapping (R3/R5): A-frag=W (row=lane&15->e), B-frag=emb
// (col=lane&15->point), D: col->point, 4 consecutive e per lane -> dwordx4.
template<bool POW2>
__global__ __launch_bounds__(256, 5) void relds_split(
    const float* __restrict__ pos,   // [B,N,3]
    const float* __restrict__ tim,   // [B,N]
    const float* __restrict__ W,     // [32,32] row-major W[e][d]
    const float* __restrict__ bias,  // [32]
    float* __restrict__ out_attn,    // f32 [P,32]
    float* __restrict__ out_emb,     // f32 [P,32]
    int N, int NN, int P, int logN, int nblk)
{
    const int tid  = threadIdx.x;
    const int lane = tid & 63;
    const int wave = tid >> 6;
    const int row  = lane & 15;   // point-slot in B/D cols; e-row for A frag
    const int kb   = lane >> 4;   // k-chunk 0..3; also e-quad for D rows

    const int side = (blockIdx.x >= (unsigned)nblk) ? 1 : 0;  // 0 = attn, 1 = emb
    const int pid  = blockIdx.x - side * nblk;
    const int wbase = pid * 256 + wave * 64;
    if (wbase >= P) return;

    // lane-uniform angle constants: d = kb*8+j; odd chunk -> freqs*1e-2; kb>=2 -> cos
    constexpr float INV2PI = 0.15915494309189535f;
    const float premul = INV2PI * ((kb & 1) ? 0.01f : 1.0f);
    const float qoff   = (kb >= 2) ? 0.25f : 0.0f;   // cos(z) = sin(z + 1/4 rev)

    if (side == 0) {
        // ---- A fragments (W) + bias quads; L1/L2-resident ----
        bf16x8 Wf[2];
        f32x4  bq[2];
        #pragma unroll
        for (int n = 0; n < 2; ++n) {
            const int e = n * 16 + row;
            const float4 wA = *reinterpret_cast<const float4*>(W + e * 32 + kb * 8);
            const float4 wB = *reinterpret_cast<const float4*>(W + e * 32 + kb * 8 + 4);
            Wf[n][0] = (__bf16)wA.x; Wf[n][1] = (__bf16)wA.y;
            Wf[n][2] = (__bf16)wA.z; Wf[n][3] = (__bf16)wA.w;
            Wf[n][4] = (__bf16)wB.x; Wf[n][5] = (__bf16)wB.y;
            Wf[n][6] = (__bf16)wB.z; Wf[n][7] = (__bf16)wB.w;
            const float4 bb = *reinterpret_cast<const float4*>(bias + n * 16 + kb * 4);
            bq[n][0] = bb.x; bq[n][1] = bb.y; bq[n][2] = bb.z; bq[n][3] = bb.w;
        }

        #pragma unroll
        for (int t = 0; t < 4; ++t) {
            const int q  = wbase + t * 16 + row;
            const int qc = (q < P) ? q : (P - 1);
            int in_n, in_m;
            if (POW2) {
                in_n = qc >> logN;
                in_m = ((qc >> (2 * logN)) << logN) | (qc & (N - 1));
            } else {
                const int b_ = qc / NN; const int r_ = qc - b_ * NN;
                const int n_ = r_ / N;  const int m_ = r_ - n_ * N;
                in_n = b_ * N + n_;     in_m = b_ * N + m_;
            }
            const float dx = pos[in_n * 3 + 0] - pos[in_m * 3 + 0];
            const float dy = pos[in_n * 3 + 1] - pos[in_m * 3 + 1];
            const float dz = pos[in_n * 3 + 2] - pos[in_m * 3 + 2];
            const float dt = (tim[in_n] - tim[in_m]) * 18.0f;  // TIME_SCALE
            const float ds2 = dx * dx + dy * dy + dz * dz - dt * dt;
            const float d   = copysignf(sqrtf(fabsf(ds2)), ds2);
            const float x   = 1024.0f * fminf(4.0f, fmaxf(-4.0f, d));
            const float xr  = x * premul;

            bf16x8 Af;
            #pragma unroll
            for (int j = 0; j < 8; ++j) {
                float rr = fmaf(xr, FREQ8[j], qoff);
                rr -= floorf(rr);
                Af[j] = (__bf16)__builtin_amdgcn_sinf(rr);
            }
            f32x4 acc0 = __builtin_amdgcn_mfma_f32_16x16x32_bf16(Wf[0], Af, bq[0], 0, 0, 0);
            f32x4 acc1 = __builtin_amdgcn_mfma_f32_16x16x32_bf16(Wf[1], Af, bq[1], 0, 0, 0);

            if (q < P) {
                float* ap = out_attn + (size_t)q * 32 + kb * 4;
                *reinterpret_cast<f32x4*>(ap)      = acc0;  // e = kb*4 .. +3
                *reinterpret_cast<f32x4*>(ap + 16) = acc1;  // e = 16 + kb*4 .. +3
            }
        }
    } else {
        #pragma unroll
        for (int t = 0; t < 4; ++t) {
            const int q  = wbase + t * 16 + row;
            const int qc = (q < P) ? q : (P - 1);
            int in_n, in_m;
            if (POW2) {
                in_n = qc >> logN;
                in_m = ((qc >> (2 * logN)) << logN) | (qc & (N - 1));
            } else {
                const int b_ = qc / NN; const int r_ = qc - b_ * NN;
                const int n_ = r_ / N;  const int m_ = r_ - n_ * N;
                in_n = b_ * N + n_;     in_m = b_ * N + m_;
            }
            const float dx = pos[in_n * 3 + 0] - pos[in_m * 3 + 0];
            const float dy = pos[in_n * 3 + 1] - pos[in_m * 3 + 1];
            const float dz = pos[in_n * 3 + 2] - pos[in_m * 3 + 2];
            const float dt = (tim[in_n] - tim[in_m]) * 18.0f;
            const float ds2 = dx * dx + dy * dy + dz * dz - dt * dt;
            const float d   = copysignf(sqrtf(fabsf(ds2)), ds2);
            const float x   = 1024.0f * fminf(4.0f, fmaxf(-4.0f, d));
            const float xr  = x * premul;

            float v[8];
            #pragma unroll
            for (int j = 0; j < 8; ++j) {
                float rr = fmaf(xr, FREQ8[j], qoff);
                rr -= floorf(rr);
                v[j] = __builtin_amdgcn_sinf(rr);
            }

            if (q < P) {  // lane owns dims kb*8..kb*8+7 of point q
                float* ep = out_emb + (size_t)q * 32 + kb * 8;
                f32x4 e0 = { v[0], v[1], v[2], v[3] };
                f32x4 e1 = { v[4], v[5], v[6], v[7] };
                reinterpret_cast<f32x4*>(ep)[0] = e0;
                reinterpret_cast<f32x4*>(ep)[1] = e1;
            }
        }
    }
}

extern "C" void kernel_launch(void* const* d_in, const int* in_sizes, int n_in,
                              void* d_out, int out_size, void* d_ws, size_t ws_size,
                              hipStream_t stream) {
    const float* pos  = (const float*)d_in[0];
    const float* tim  = (const float*)d_in[1];
    const float* W    = (const float*)d_in[2];
    const float* bias = (const float*)d_in[3];

    const int BN = in_sizes[1];          // B*N
    const int P  = out_size / 64;        // B*N*N
    const int N  = P / BN;
    const int NN = N * N;

    int logN = 0;
    while ((1 << logN) < N) ++logN;
    const bool pow2 = ((1 << logN) == N);

    float* out_attn = (float*)d_out;
    float* out_emb  = out_attn + (size_t)out_size / 2;

    const int nblk = (P + 255) / 256;
    const int grid = 2 * nblk;           // blocks [0,nblk): attn, [nblk,2nblk): emb
    if (pow2)
        relds_split<true><<<grid, 256, 0, stream>>>(pos, tim, W, bias, out_attn, out_emb, N, NN, P, logN, nblk);
    else
        relds_split<false><<<grid, 256, 0, stream>>>(pos, tim, W, bias, out_attn, out_emb, N, NN, P, logN, nblk);
}